// Round 9
// baseline (21.734 us; speedup 1.0000x reference)
//
#include <hip/hip_runtime.h>
#include <math.h>

#define BATCH 2
#define LLEN  2080
#define MCH   2
#define TT    51
#define FF    80
#define HOP   40
#define KW    1600
#define OUTL  2040
#define NT    640
#define NS    52                   // output strips of 40 samples
#define NB    (BATCH * NS * MCH)   // 208 blocks
#define ZROW  161                  // padded Z row stride (float2)
#define PI_F  3.14159265358979323846f

// One block per (b, strip s, m). Two delta spectra (frames s and s-1, roll
// wraparound), computed with R3's proven 5-wide sliding window run twice,
// then half-iDFTs, overlap-add, residual, slice. Single launch.
__global__ __launch_bounds__(NT) void mono_kernel(
    const float* __restrict__ xr, const float* __restrict__ xi,
    const float* __restrict__ ti,
    const float* __restrict__ wr, const float* __restrict__ wi,
    const float* __restrict__ br, const float* __restrict__ bi,
    float* __restrict__ out, int out_size)
{
    __shared__ float2 xs[4 * FF];        // samples, 4 frame slots
    __shared__ float2 tw[FF];            // e^{+i 2pi r/80} exact (iDFT)
    __shared__ float2 Ysh[4][2 * FF];    // double-stored spectra: [j]=Y[(j-20)%80]
    __shared__ float2 Wsh[KW];           // w [n1][n2], reg-staged
    __shared__ float2 Zall[2][40][ZROW]; // Z rows for deltas A,B
    __shared__ float2 dvec[2 * FF];      // two delta spectra

    float2* flat = &Zall[0][0][0];       // overlay scratch (pass-local, 0..3840)

    int tid = threadIdx.x;
    int bid = blockIdx.x;
    int b   = bid / (NS * MCH);
    int rem = bid % (NS * MCH);
    int s   = rem / MCH;
    int mi  = rem % MCH;

    bool dAv = (s <= TT - 1);            // delta[s] exists
    bool dBv = (s >= 1);                 // delta[s-1] exists
    int cA = dAv ? s : TT - 1;           // clamped (unused values masked later)
    int pA = (cA + TT - 1) % TT;
    int cB = dBv ? s - 1 : 0;
    int pB = (cB + TT - 1) % TT;

    float bre = br[0], bim = bi[0];

    // ---- w reg-stage (latency hides under phases 1-2) ----
    float2 wreg0 = make_float2(wr[tid],      wi[tid]);
    float2 wreg1 = make_float2(wr[tid + NT], wi[tid + NT]);
    float2 wreg2 = make_float2(0.f, 0.f);
    if (tid < KW - 2 * NT)
        wreg2 = make_float2(wr[tid + 2 * NT], wi[tid + 2 * NT]);

    // ---- Phase 0: samples for 4 slots (320 thr) + tw table (80 thr) ----
    if (tid < 4 * FF) {
        int slot = tid / FF, j = tid % FF;
        int tslot = (slot == 0) ? cA : (slot == 1) ? pA : (slot == 2) ? cB : pB;
        int g = (b * LLEN + tslot * HOP + j) * MCH + mi;
        xs[tid] = make_float2(xr[g], xi[g]);
    } else if (tid < 5 * FF) {
        int jj = tid - 4 * FF;
        float sn, cs;
        sincosf((2.0f * PI_F / FF) * (float)jj, &sn, &cs);
        tw[jj] = make_float2(cs, sn);
    }
    __syncthreads();   // A

    // ---- Phase 1: STFT of 4 slots; 320 outputs x 2 partials x 40 MACs ----
    {
        int o    = tid >> 1;      // 0..319
        int pq   = tid & 1;
        int slot = o / FF;
        int ff   = o % FF;
        const float2* xb = &xs[slot * FF];

        // seed at j0 = pq*40: e^{-i pi ff pq} = (-1)^(ff*pq), exact
        float2 tv = ((ff & pq) & 1) ? make_float2(-1.f, 0.f) : make_float2(1.f, 0.f);
        float sp, cp;
        sincosf(-(2.0f * PI_F / FF) * (float)ff, &sp, &cp);
        float2 st = make_float2(cp, sp);     // e^{-i 2pi ff/80}

        float2 a = make_float2(0.f, 0.f);
        int j = pq * 40;
        #pragma unroll 4
        for (int i = 0; i < 40; ++i, ++j) {
            float2 xv = xb[j];
            a.x += xv.x * tv.x - xv.y * tv.y;
            a.y += xv.x * tv.y + xv.y * tv.x;
            float nx = tv.x * st.x - tv.y * st.y;
            tv.y = tv.x * st.y + tv.y * st.x;
            tv.x = nx;
        }
        a.x += __shfl_xor(a.x, 1);
        a.y += __shfl_xor(a.y, 1);
        if (pq == 0) {
            Ysh[slot][ff + 20] = a;
            Ysh[slot][(ff < 60) ? (ff + 100) : (ff - 60)] = a;
        }
    }
    __syncthreads();   // B

    // ---- Phase 2: Z rows for both deltas (6400 values, 10/thread) ----
    #pragma unroll
    for (int i = 0; i < 10; ++i) {
        int zi = tid + i * NT;        // 0..6399
        int d  = zi / 3200;
        int rr = zi % 3200;
        int jn = rr / FF;
        int g  = rr % FF;
        const float2* Ya = Ysh[2 * d];
        const float2* Yp = Ysh[2 * d + 1];
        float2 a  = Ya[g + 20], bm = Ya[g - jn + 40];
        float2 cc = Yp[g + 20], dm = Yp[g - jn + 40];
        float zre = a.x * bm.x + a.y * bm.y + cc.x * dm.x + cc.y * dm.y;
        float zim = a.y * bm.x - a.x * bm.y + cc.y * dm.x - cc.x * dm.y;
        float2 z = make_float2(zre, zim);
        Zall[d][jn][g + 20] = z;
        Zall[d][jn][(g < 60) ? (g + 100) : (g - 60)] = z;
    }
    // stage W into LDS (global loads long since landed)
    Wsh[tid]      = wreg0;
    Wsh[tid + NT] = wreg1;
    if (tid < KW - 2 * NT) Wsh[tid + 2 * NT] = wreg2;
    __syncthreads();   // C

    // ---- Phase 3 + reduce: two sequential passes (R3's 5-wide window) ----
    for (int d = 0; d < 2; ++d) {
        float2 o0, o1, o2, o3, o4;
        int jn = tid >> 4;          // n2 index 0..39
        int fg = tid & 15;
        int fb = fg * 5;
        {
            const float2* zz = &Zall[d][jn][0];
            const float2* Ya = Ysh[2 * d];

            float2 S0 = make_float2(0.f,0.f), S1 = S0, S2 = S0, S3 = S0, S4 = S0;
            float2 w0 = zz[fb + 40], w1 = zz[fb + 41], w2 = zz[fb + 42],
                   w3 = zz[fb + 43], w4 = zz[fb + 44];
            #pragma unroll
            for (int jn1 = 0; jn1 < 40; ++jn1) {
                float2 wv = Wsh[jn1 * 40 + jn];
                S0.x += wv.x * w0.x - wv.y * w0.y;  S0.y += wv.x * w0.y + wv.y * w0.x;
                S1.x += wv.x * w1.x - wv.y * w1.y;  S1.y += wv.x * w1.y + wv.y * w1.x;
                S2.x += wv.x * w2.x - wv.y * w2.y;  S2.y += wv.x * w2.y + wv.y * w2.x;
                S3.x += wv.x * w3.x - wv.y * w3.y;  S3.y += wv.x * w3.y + wv.y * w3.x;
                S4.x += wv.x * w4.x - wv.y * w4.y;  S4.y += wv.x * w4.y + wv.y * w4.x;
                if (jn1 < 39) {
                    float2 nv = zz[fb + 39 - jn1];
                    w4 = w3; w3 = w2; w2 = w1; w1 = w0; w0 = nv;
                }
            }
            float2 y;
            y = Ya[fb + 0 - jn + 40]; o0 = make_float2(y.x*S0.x - y.y*S0.y, y.x*S0.y + y.y*S0.x);
            y = Ya[fb + 1 - jn + 40]; o1 = make_float2(y.x*S1.x - y.y*S1.y, y.x*S1.y + y.y*S1.x);
            y = Ya[fb + 2 - jn + 40]; o2 = make_float2(y.x*S2.x - y.y*S2.y, y.x*S2.y + y.y*S2.x);
            y = Ya[fb + 3 - jn + 40]; o3 = make_float2(y.x*S3.x - y.y*S3.y, y.x*S3.y + y.y*S3.x);
            y = Ya[fb + 4 - jn + 40]; o4 = make_float2(y.x*S4.x - y.y*S4.y, y.x*S4.y + y.y*S4.x);
        }
        __syncthreads();   // E(d): all Zall[d] reads done; overlay region free
        flat[jn * FF + fb + 0] = o0;
        flat[jn * FF + fb + 1] = o1;
        flat[jn * FF + fb + 2] = o2;
        flat[jn * FF + fb + 3] = o3;
        flat[jn * FF + fb + 4] = o4;
        __syncthreads();   // F(d)

        // tree-reduce 40 n2-partials: stage 1 (640 thr, 5 rows each)
        {
            int f = tid % FF;
            int p = tid / FF;      // 0..7
            float2 sum = make_float2(0.f, 0.f);
            #pragma unroll
            for (int q2 = 0; q2 < 5; ++q2) {
                float2 v = flat[(p * 5 + q2) * FF + f];
                sum.x += v.x; sum.y += v.y;
            }
            flat[3200 + p * FF + f] = sum;
        }
        __syncthreads();   // G(d)
        if (tid < FF) {
            float2 sum = make_float2(bre, bim);
            #pragma unroll
            for (int p = 0; p < 8; ++p) {
                float2 v = flat[3200 + p * FF + tid];
                sum.x += v.x; sum.y += v.y;
            }
            dvec[d * FF + tid] = sum;
        }
        __syncthreads();   // H(d)
    }

    // ---- Phase 4: half-iDFTs; (d, 40 samples, 8 partials) x 10 MACs ----
    {
        int d   = tid / 320;
        int rr  = tid % 320;
        int j40 = rr >> 3;
        int p8  = rr & 7;
        int j   = j40 + 40 * d;       // delta A: j in [0,40); delta B: [40,80)
        float2 a = make_float2(0.f, 0.f);
        int f0 = p8 * 10;
        int r  = (j * f0) % FF;
        #pragma unroll 5
        for (int i = 0; i < 10; ++i) {
            float2 dv = dvec[d * FF + f0 + i];
            float2 tv = tw[r];        // e^{+i 2pi j f/80}
            a.x += dv.x * tv.x - dv.y * tv.y;
            a.y += dv.x * tv.y + dv.y * tv.x;
            r += j; if (r >= FF) r -= FF;
        }
        flat[(d * 40 + j40) * 8 + p8] = a;
    }
    __syncthreads();   // M

    // ---- final: overlap-add + cov + residual + slice, 40 threads ----
    if (tid < 40) {
        int j40 = tid;
        int l = 40 * s + j40;
        if (l >= 20 && l < LLEN - 20) {
            float2 acc = make_float2(0.f, 0.f);
            float cov = 0.f;
            if (dAv) {
                #pragma unroll
                for (int p = 0; p < 8; ++p) {
                    float2 v = flat[j40 * 8 + p];
                    acc.x += v.x; acc.y += v.y;
                }
                cov += 1.f;
            }
            if (dBv) {
                #pragma unroll
                for (int p = 0; p < 8; ++p) {
                    float2 v = flat[(40 + j40) * 8 + p];
                    acc.x += v.x; acc.y += v.y;
                }
                cov += 1.f;
            }
            float P   = exp2f(ti[b * 4] * 0.33219280948873623f) * 0.5f;  // 10^(x/10)/m
            float inv = 1.0f / ((float)FF * cov);
            float ar = acc.x * inv, ai = acc.y * inv;
            int gi = (b * LLEN + l) * MCH + mi;
            int lo = l - 20;
            int p  = (b * OUTL + lo) * MCH + mi;
            const int tot = BATCH * OUTL * MCH;
            float outr = xr[gi] + ar * P;
            if (out_size == tot) {
                out[p] = outr;
            } else {
                out[p * 2]     = outr;
                out[p * 2 + 1] = xi[gi] + ai * P;
            }
        }
    }
}

extern "C" void kernel_launch(void* const* d_in, const int* in_sizes, int n_in,
                              void* d_out, int out_size, void* d_ws, size_t ws_size,
                              hipStream_t stream)
{
    const float* xr = (const float*)d_in[0];
    const float* xi = (const float*)d_in[1];
    const float* ti = (const float*)d_in[2];
    const float* wr = (const float*)d_in[3];
    const float* wi = (const float*)d_in[4];
    const float* br = (const float*)d_in[5];
    const float* bi = (const float*)d_in[6];

    mono_kernel<<<NB, NT, 0, stream>>>(xr, xi, ti, wr, wi, br, bi,
                                       (float*)d_out, out_size);
}

// Round 10
// 20.527 us; speedup vs baseline: 1.0588x; 1.0588x over previous
//
#include <hip/hip_runtime.h>
#include <math.h>

#define BATCH 2
#define LLEN  2080
#define MCH   2
#define TT    51
#define FF    80
#define HOP   40
#define KW    1600
#define OUTL  2040
#define NT    320                   // threads per half-block (5 waves)
#define NHB   (BATCH * TT * MCH * 2) // 408 half-blocks
#define NFR   (BATCH * TT * MCH)     // 204 frames
#define ZROW  161                    // padded Z row stride (float2)
#define PI_F  3.14159265358979323846f

// ---------------- Kernel 1: half-delta per block (n2 split 2-way) ----------------
// block = (b,t,m,h): computes delta contribution of n2-range [h*20, h*20+20),
// iDFTs it (linear), writes partial Fr half h. 408 blocks x 320 threads.
__global__ __launch_bounds__(NT) void fused_k1(
    const float* __restrict__ xr, const float* __restrict__ xi,
    const float* __restrict__ wr, const float* __restrict__ wi,
    const float* __restrict__ br, const float* __restrict__ bi,
    float2* __restrict__ FrH)       // [2][204][80]
{
    __shared__ float2 xs[2 * FF];      // frame t, frame t-1
    __shared__ float2 tw[FF];          // e^{+i 2pi r/80} exact
    __shared__ float2 Yt2[2 * FF];     // double-stored Yt
    __shared__ float2 Yp[FF];
    __shared__ float2 Wsh[40 * 20];    // w[n1][jn_local], this half's columns
    __shared__ float2 Zall[20][ZROW];  // padded Z rows; overlaid by reductions
    __shared__ float2 dvec[FF];

    float2* flat = &Zall[0][0];        // 3220-entry overlay scratch

    int tid = threadIdx.x;
    int bid = blockIdx.x;
    int h   = bid & 1;
    int fid = bid >> 1;                // frame id 0..203
    int b   = fid / (TT * MCH);
    int rem = fid % (TT * MCH);
    int t   = rem / MCH;
    int mi  = rem % MCH;
    int tp  = (t + TT - 1) % TT;

    float bre = br[0], bim = bi[0];

    // ---- Phase 0: samples (160 thr) + tw table (80 thr) + w half (all) ----
    if (tid < 2 * FF) {
        int frm = tid / FF, j = tid % FF;
        int tt  = (frm == 0) ? t : tp;
        int g = (b * LLEN + tt * HOP + j) * MCH + mi;
        xs[tid] = make_float2(xr[g], xi[g]);
    } else if (tid < 240) {
        int jj = tid - 160;
        float s, c;
        sincosf((2.0f * PI_F / FF) * (float)jj, &s, &c);
        tw[jj] = make_float2(c, s);
    }
    for (int k = tid; k < 800; k += NT) {
        int jn1 = k / 20, jl = k % 20;
        int src = jn1 * 40 + h * 20 + jl;
        Wsh[k] = make_float2(wr[src], wi[src]);
    }
    __syncthreads();   // A

    // ---- Phase 1: STFT both frames; 160 outputs x 2 partials x 40 MACs ----
    {
        int o    = tid >> 1;       // 0..159
        int pq   = tid & 1;
        int ff   = o % FF;
        int frm  = o / FF;
        const float2* xb = &xs[frm * FF];
        float2 a = make_float2(0.f, 0.f);
        int j = pq * 40;
        int r = (ff * j) % FF;
        #pragma unroll 5
        for (int i = 0; i < 40; ++i, ++j) {
            float2 xv = xb[j];
            float2 tv = tw[r];             // conj -> e^{-i 2pi ff j/80}
            a.x += xv.x * tv.x + xv.y * tv.y;
            a.y += xv.y * tv.x - xv.x * tv.y;
            r += ff; if (r >= FF) r -= FF;
        }
        flat[pq * 160 + o] = a;
    }
    __syncthreads();   // B
    if (tid < 2 * FF) {
        float2 v0 = flat[tid], v1 = flat[160 + tid];
        float2 s = make_float2(v0.x + v1.x, v0.y + v1.y);
        if (tid < FF) {
            Yt2[tid + 20] = s;
            Yt2[(tid < 60) ? (tid + 100) : (tid - 60)] = s;
        } else {
            Yp[tid - FF] = s;
        }
    }
    __syncthreads();   // C

    // ---- Phase 2: build this half's 20 Z rows (1600 values, 5/thread) ----
    for (int i = 0; i < 5; ++i) {
        int zi = tid + i * NT;         // 0..1599
        int jl = zi / FF;
        int g  = zi % FF;
        int n2 = h * 20 + jl - 20;
        float2 a  = Yt2[g + 20], bm = Yt2[g - n2 + 20];
        float2 cc = Yp[g],       dm = Yp[(g - n2 + FF) % FF];
        float zre = a.x * bm.x + a.y * bm.y + cc.x * dm.x + cc.y * dm.y;
        float zim = a.y * bm.x - a.x * bm.y + cc.y * dm.x - cc.x * dm.y;
        float2 z = make_float2(zre, zim);
        Zall[jl][g + 20] = z;
        Zall[jl][(g < 60) ? (g + 100) : (g - 60)] = z;
    }
    __syncthreads();   // D

    // ---- Phase 3: R3's 5-wide register sliding window; 20 jn x 16 fg ----
    float2 o0, o1, o2, o3, o4;
    int jl, fb;
    {
        jl = tid >> 4;           // local n2 index 0..19
        int fg = tid & 15;
        fb = fg * 5;
        int jn = h * 20 + jl;    // global n2 index
        const float2* zz = &Zall[jl][0];

        float2 S0 = make_float2(0.f,0.f), S1 = S0, S2 = S0, S3 = S0, S4 = S0;
        float2 w0 = zz[fb + 40], w1 = zz[fb + 41], w2 = zz[fb + 42],
               w3 = zz[fb + 43], w4 = zz[fb + 44];
        #pragma unroll
        for (int jn1 = 0; jn1 < 40; ++jn1) {
            float2 wv = Wsh[jn1 * 20 + jl];
            S0.x += wv.x * w0.x - wv.y * w0.y;  S0.y += wv.x * w0.y + wv.y * w0.x;
            S1.x += wv.x * w1.x - wv.y * w1.y;  S1.y += wv.x * w1.y + wv.y * w1.x;
            S2.x += wv.x * w2.x - wv.y * w2.y;  S2.y += wv.x * w2.y + wv.y * w2.x;
            S3.x += wv.x * w3.x - wv.y * w3.y;  S3.y += wv.x * w3.y + wv.y * w3.x;
            S4.x += wv.x * w4.x - wv.y * w4.y;  S4.y += wv.x * w4.y + wv.y * w4.x;
            if (jn1 < 39) {
                float2 nv = zz[fb + 39 - jn1];
                w4 = w3; w3 = w2; w2 = w1; w1 = w0; w0 = nv;
            }
        }
        float2 y;
        y = Yt2[fb + 0 - jn + 40]; o0 = make_float2(y.x*S0.x - y.y*S0.y, y.x*S0.y + y.y*S0.x);
        y = Yt2[fb + 1 - jn + 40]; o1 = make_float2(y.x*S1.x - y.y*S1.y, y.x*S1.y + y.y*S1.x);
        y = Yt2[fb + 2 - jn + 40]; o2 = make_float2(y.x*S2.x - y.y*S2.y, y.x*S2.y + y.y*S2.x);
        y = Yt2[fb + 3 - jn + 40]; o3 = make_float2(y.x*S3.x - y.y*S3.y, y.x*S3.y + y.y*S3.x);
        y = Yt2[fb + 4 - jn + 40]; o4 = make_float2(y.x*S4.x - y.y*S4.y, y.x*S4.y + y.y*S4.x);
    }
    __syncthreads();   // E: all Zall reads done before overlay writes
    flat[jl * FF + fb + 0] = o0;
    flat[jl * FF + fb + 1] = o1;
    flat[jl * FF + fb + 2] = o2;
    flat[jl * FF + fb + 3] = o3;
    flat[jl * FF + fb + 4] = o4;
    __syncthreads();   // F

    // ---- tree-reduce 20 n2-partials: stage 1 (320 thr, 5 rows each) ----
    {
        int f = tid % FF;
        int p = tid / FF;      // 0..3
        float2 s = make_float2(0.f, 0.f);
        #pragma unroll
        for (int q2 = 0; q2 < 5; ++q2) {
            float2 v = flat[(p * 5 + q2) * FF + f];
            s.x += v.x; s.y += v.y;
        }
        flat[1600 + p * FF + f] = s;
    }
    __syncthreads();   // G
    if (tid < FF) {
        float2 s = (h == 0) ? make_float2(bre, bim) : make_float2(0.f, 0.f);
        #pragma unroll
        for (int p = 0; p < 4; ++p) {
            float2 v = flat[1600 + p * FF + tid];
            s.x += v.x; s.y += v.y;
        }
        dvec[tid] = s;
    }
    __syncthreads();   // H

    // ---- Phase 4: iDFT of partial spectrum; 80 samples x 4 partials x 20 MACs ----
    {
        int j  = tid >> 2;     // time sample 0..79
        int p4 = tid & 3;
        float2 a = make_float2(0.f, 0.f);
        int f0 = p4 * 20;
        int r  = (j * f0) % FF;
        #pragma unroll 5
        for (int i = 0; i < 20; ++i) {
            float2 dv = dvec[f0 + i];
            float2 tv = tw[r];             // e^{+i 2pi j f/80}
            a.x += dv.x * tv.x - dv.y * tv.y;
            a.y += dv.x * tv.y + dv.y * tv.x;
            r += j; if (r >= FF) r -= FF;
        }
        flat[p4 * FF + j] = a;
    }
    __syncthreads();   // I
    if (tid < FF) {
        float2 s = make_float2(0.f, 0.f);
        #pragma unroll
        for (int p = 0; p < 4; ++p) {
            float2 v = flat[p * FF + tid];
            s.x += v.x; s.y += v.y;
        }
        s.x *= (1.0f / FF);
        s.y *= (1.0f / FF);
        FrH[(h * NFR + fid) * FF + tid] = s;
    }
}

// ---------------- Kernel 2: sum halves, overlap-add, cov, residual, slice ----------------
__global__ void out_kernel(
    const float* __restrict__ xr, const float* __restrict__ xi,
    const float* __restrict__ ti, const float2* __restrict__ FrH,
    float* __restrict__ out, int out_size)
{
    int idx = blockIdx.x * blockDim.x + threadIdx.x;
    int tot = BATCH * OUTL * MCH;
    if (idx >= tot) return;
    int mi  = idx % MCH;
    int rem = idx / MCH;
    int lo  = rem % OUTL;
    int b   = rem / OUTL;
    int l   = lo + 20;

    float P = exp2f(ti[b * 4] * 0.33219280948873623f) * 0.5f;  // 10^(x/10)/m

    int t1 = l / HOP;
    int t0 = t1 - 1;
    float2 acc = make_float2(0.f, 0.f);
    float cov = 0.f;
    if (t1 <= TT - 1) {
        int base = ((b * TT + t1) * MCH + mi) * FF + (l - HOP * t1);
        float2 v0 = FrH[base];
        float2 v1 = FrH[NFR * FF + base];
        acc.x += v0.x + v1.x; acc.y += v0.y + v1.y; cov += 1.f;
    }
    if (t0 >= 0) {
        int base = ((b * TT + t0) * MCH + mi) * FF + (l - HOP * t0);
        float2 v0 = FrH[base];
        float2 v1 = FrH[NFR * FF + base];
        acc.x += v0.x + v1.x; acc.y += v0.y + v1.y; cov += 1.f;
    }
    float inv = 1.0f / cov;
    acc.x *= inv; acc.y *= inv;

    int gi = (b * LLEN + l) * MCH + mi;
    float outr = xr[gi] + acc.x * P;
    if (out_size == tot) {
        out[idx] = outr;
    } else {
        float outi = xi[gi] + acc.y * P;
        out[idx * 2]     = outr;
        out[idx * 2 + 1] = outi;
    }
}

extern "C" void kernel_launch(void* const* d_in, const int* in_sizes, int n_in,
                              void* d_out, int out_size, void* d_ws, size_t ws_size,
                              hipStream_t stream)
{
    const float* xr = (const float*)d_in[0];
    const float* xi = (const float*)d_in[1];
    const float* ti = (const float*)d_in[2];
    const float* wr = (const float*)d_in[3];
    const float* wi = (const float*)d_in[4];
    const float* br = (const float*)d_in[5];
    const float* bi = (const float*)d_in[6];

    float2* FrH = (float2*)d_ws;   // 2 * 204 * 80 float2 = 261 KB

    fused_k1<<<NHB, NT, 0, stream>>>(xr, xi, wr, wi, br, bi, FrH);

    int tot = BATCH * OUTL * MCH;   // 8160
    out_kernel<<<(tot + 255) / 256, 256, 0, stream>>>(xr, xi, ti, FrH,
                                                      (float*)d_out, out_size);
}

// Round 11
// 17.974 us; speedup vs baseline: 1.2092x; 1.1420x over previous
//
#include <hip/hip_runtime.h>
#include <math.h>

#define BATCH 2
#define LLEN  2080
#define MCH   2
#define TT    51
#define FF    80
#define HOP   40
#define KW    1600
#define OUTL  2040
#define NT    832                  // 13 waves; phase 3 uses 800 (40 jn x 20 fg)
#define NB    (BATCH * TT * MCH)   // 204
#define ZROW  161                  // padded Z row stride (float2)
#define PI_F  3.14159265358979323846f

// ---------------- Kernel 1: STFT + delta + iDFT, 204 blocks x 832 thr ----------------
__global__ __launch_bounds__(NT) void fused_k1(
    const float* __restrict__ xr, const float* __restrict__ xi,
    const float* __restrict__ wr, const float* __restrict__ wi,
    const float* __restrict__ br, const float* __restrict__ bi,
    float2* __restrict__ Fr)
{
    __shared__ float2 xs[2 * FF];      // frame t [0:80), frame t-1 [80:160)
    __shared__ float2 tw[FF];          // e^{+i 2pi r/80} exact table
    __shared__ float2 Yt2[2 * FF];     // double-stored Yt: Yt2[j] = Yt[(j-20)%80]
    __shared__ float2 Yp[FF];
    __shared__ float2 Wsh[KW];         // w, [n1][n2]
    __shared__ float2 Zall[40][ZROW];  // padded Z rows (flat overlay pre-phase-2 only)
    __shared__ float2 part3[40][81];   // phase-3 outputs (dedicated: no overlay barrier)
    __shared__ float2 red2[8][FF];     // stage-1 n2-reduce / phase-4 partials
    __shared__ float2 dvec[FF];

    float2* flat = &Zall[0][0];        // scratch for phase-1 partials (pre-Zall build)

    int tid = threadIdx.x;
    int bid = blockIdx.x;
    int b   = bid / (TT * MCH);
    int rem = bid % (TT * MCH);
    int t   = rem / MCH;
    int mi  = rem % MCH;
    int tp  = (t + TT - 1) % TT;

    float bre = br[0], bim = bi[0];

    // ---- Phase 0: samples (160 thr), tw (80 thr), W (all, 2 strided iters) ----
    if (tid < 2 * FF) {
        int frm = tid / FF, j = tid % FF;
        int tt  = (frm == 0) ? t : tp;
        int g = (b * LLEN + tt * HOP + j) * MCH + mi;
        xs[tid] = make_float2(xr[g], xi[g]);
    } else if (tid < 240) {
        int jj = tid - 160;
        float s, c;
        sincosf((2.0f * PI_F / FF) * (float)jj, &s, &c);
        tw[jj] = make_float2(c, s);
    }
    for (int k = tid; k < KW; k += NT)
        Wsh[k] = make_float2(wr[k], wi[k]);
    __syncthreads();   // A

    // ---- Phase 1: STFT both frames; 160 outputs x 4 partials x 20 MACs ----
    if (tid < 640) {
        int o    = tid >> 2;       // 0..159
        int pq   = tid & 3;
        int ff   = o % FF;
        int frm  = o / FF;
        const float2* xb = &xs[frm * FF];
        float2 a = make_float2(0.f, 0.f);
        int j = pq * 20;
        int r = (ff * j) % FF;
        #pragma unroll 5
        for (int i = 0; i < 20; ++i, ++j) {
            float2 xv = xb[j];
            float2 tv = tw[r];              // conj -> e^{-i 2pi ff j/80}
            a.x += xv.x * tv.x + xv.y * tv.y;
            a.y += xv.y * tv.x - xv.x * tv.y;
            r += ff; if (r >= FF) r -= FF;
        }
        flat[pq * 160 + o] = a;
    }
    __syncthreads();   // B
    if (tid < 2 * FF) {
        float2 s = make_float2(0.f, 0.f);
        #pragma unroll
        for (int p = 0; p < 4; ++p) {
            float2 v = flat[p * 160 + tid];
            s.x += v.x; s.y += v.y;
        }
        if (tid < FF) {
            Yt2[tid + 20] = s;
            Yt2[(tid < 60) ? (tid + 100) : (tid - 60)] = s;
        } else {
            Yp[tid - FF] = s;
        }
    }
    __syncthreads();   // C

    // ---- Phase 2: build 40 Z rows (3200 values, strided), double-stored ----
    for (int zi = tid; zi < 3200; zi += NT) {
        int jn = zi / FF;
        int g  = zi % FF;
        int n2 = jn - 20;
        int gm = g - n2; if (gm >= FF) gm -= FF; if (gm < 0) gm += FF;
        float2 a  = Yt2[g + 20], bm = Yt2[gm + 20];
        float2 cc = Yp[g],       dm = Yp[gm];
        float zre = a.x * bm.x + a.y * bm.y + cc.x * dm.x + cc.y * dm.y;
        float zim = a.y * bm.x - a.x * bm.y + cc.y * dm.x - cc.x * dm.y;
        float2 z = make_float2(zre, zim);
        Zall[jn][g + 20] = z;
        Zall[jn][(g < 60) ? (g + 100) : (g - 60)] = z;
    }
    __syncthreads();   // D

    // ---- Phase 3: 4-wide register sliding window; 40 jn x 20 fg = 800 thr ----
    if (tid < 800) {
        int jn = tid % 40;          // n2 index (consecutive across lanes)
        int fg = tid / 40;          // 0..19
        int fb = fg * 4;
        const float2* zz = &Zall[jn][0];

        float2 S0 = make_float2(0.f,0.f), S1 = S0, S2 = S0, S3 = S0;
        float2 w0 = zz[fb + 40], w1 = zz[fb + 41], w2 = zz[fb + 42], w3 = zz[fb + 43];
        #pragma unroll
        for (int jn1 = 0; jn1 < 40; ++jn1) {
            float2 wv = Wsh[jn1 * 40 + jn];
            S0.x += wv.x * w0.x - wv.y * w0.y;  S0.y += wv.x * w0.y + wv.y * w0.x;
            S1.x += wv.x * w1.x - wv.y * w1.y;  S1.y += wv.x * w1.y + wv.y * w1.x;
            S2.x += wv.x * w2.x - wv.y * w2.y;  S2.y += wv.x * w2.y + wv.y * w2.x;
            S3.x += wv.x * w3.x - wv.y * w3.y;  S3.y += wv.x * w3.y + wv.y * w3.x;
            if (jn1 < 39) {
                float2 nv = zz[fb + 39 - jn1];
                w3 = w2; w2 = w1; w1 = w0; w0 = nv;
            }
        }
        float2 y;
        y = Yt2[fb + 0 - jn + 40];
        part3[jn][fb + 0] = make_float2(y.x*S0.x - y.y*S0.y, y.x*S0.y + y.y*S0.x);
        y = Yt2[fb + 1 - jn + 40];
        part3[jn][fb + 1] = make_float2(y.x*S1.x - y.y*S1.y, y.x*S1.y + y.y*S1.x);
        y = Yt2[fb + 2 - jn + 40];
        part3[jn][fb + 2] = make_float2(y.x*S2.x - y.y*S2.y, y.x*S2.y + y.y*S2.x);
        y = Yt2[fb + 3 - jn + 40];
        part3[jn][fb + 3] = make_float2(y.x*S3.x - y.y*S3.y, y.x*S3.y + y.y*S3.x);
    }
    __syncthreads();   // F

    // ---- tree-reduce 40 n2-partials: stage 1 (640 thr, 5 rows each) ----
    if (tid < 640) {
        int f = tid % FF;
        int p = tid / FF;      // 0..7
        float2 s = make_float2(0.f, 0.f);
        #pragma unroll
        for (int q2 = 0; q2 < 5; ++q2) {
            float2 v = part3[p * 5 + q2][f];
            s.x += v.x; s.y += v.y;
        }
        red2[p][f] = s;
    }
    __syncthreads();   // G
    if (tid < FF) {
        float2 s = make_float2(bre, bim);
        #pragma unroll
        for (int p = 0; p < 8; ++p) {
            float2 v = red2[p][tid];
            s.x += v.x; s.y += v.y;
        }
        dvec[tid] = s;
    }
    __syncthreads();   // H

    // ---- Phase 4: iDFT; 80 samples x 8 partials x 10 MACs ----
    if (tid < 640) {
        int j  = tid >> 3;     // time sample 0..79
        int p8 = tid & 7;
        float2 a = make_float2(0.f, 0.f);
        int f0 = p8 * 10;
        int r  = (j * f0) % FF;
        #pragma unroll 5
        for (int i = 0; i < 10; ++i) {
            float2 dv = dvec[f0 + i];
            float2 tv = tw[r];             // e^{+i 2pi j f/80}
            a.x += dv.x * tv.x - dv.y * tv.y;
            a.y += dv.x * tv.y + dv.y * tv.x;
            r += j; if (r >= FF) r -= FF;
        }
        red2[p8][j] = a;
    }
    __syncthreads();   // I
    if (tid < FF) {
        float2 s = make_float2(0.f, 0.f);
        #pragma unroll
        for (int p = 0; p < 8; ++p) {
            float2 v = red2[p][tid];
            s.x += v.x; s.y += v.y;
        }
        s.x *= (1.0f / FF);
        s.y *= (1.0f / FF);
        Fr[((b * TT + t) * MCH + mi) * FF + tid] = s;
    }
}

// ---------------- Kernel 2: overlap-add, cov, residual, slice ----------------
// 64-thread blocks x 128 -> spread latency-bound work over 128 CUs
__global__ __launch_bounds__(64) void out_kernel(
    const float* __restrict__ xr, const float* __restrict__ xi,
    const float* __restrict__ ti, const float2* __restrict__ Fr,
    float* __restrict__ out, int out_size)
{
    int idx = blockIdx.x * 64 + threadIdx.x;
    int tot = BATCH * OUTL * MCH;
    if (idx >= tot) return;
    int mi  = idx % MCH;
    int rem = idx / MCH;
    int lo  = rem % OUTL;
    int b   = rem / OUTL;
    int l   = lo + 20;

    float P = exp2f(ti[b * 4] * 0.33219280948873623f) * 0.5f;  // 10^(x/10)/m

    int t1 = l / HOP;
    int t0 = t1 - 1;
    float2 acc = make_float2(0.f, 0.f);
    float cov = 0.f;
    if (t1 <= TT - 1) {
        float2 v = Fr[((b * TT + t1) * MCH + mi) * FF + (l - HOP * t1)];
        acc.x += v.x; acc.y += v.y; cov += 1.f;
    }
    if (t0 >= 0) {
        float2 v = Fr[((b * TT + t0) * MCH + mi) * FF + (l - HOP * t0)];
        acc.x += v.x; acc.y += v.y; cov += 1.f;
    }
    float inv = 1.0f / cov;
    acc.x *= inv; acc.y *= inv;

    int gi = (b * LLEN + l) * MCH + mi;
    float outr = xr[gi] + acc.x * P;
    if (out_size == tot) {
        out[idx] = outr;
    } else {
        float outi = xi[gi] + acc.y * P;
        out[idx * 2]     = outr;
        out[idx * 2 + 1] = outi;
    }
}

extern "C" void kernel_launch(void* const* d_in, const int* in_sizes, int n_in,
                              void* d_out, int out_size, void* d_ws, size_t ws_size,
                              hipStream_t stream)
{
    const float* xr = (const float*)d_in[0];
    const float* xi = (const float*)d_in[1];
    const float* ti = (const float*)d_in[2];
    const float* wr = (const float*)d_in[3];
    const float* wi = (const float*)d_in[4];
    const float* br = (const float*)d_in[5];
    const float* bi = (const float*)d_in[6];

    float2* Fr = (float2*)d_ws;   // 204*80 float2 = 130.6 KB

    fused_k1<<<NB, NT, 0, stream>>>(xr, xi, wr, wi, br, bi, Fr);

    int tot = BATCH * OUTL * MCH;   // 8160
    out_kernel<<<(tot + 63) / 64, 64, 0, stream>>>(xr, xi, ti, Fr,
                                                   (float*)d_out, out_size);
}